// Round 1
// baseline (1268.651 us; speedup 1.0000x reference)
//
#include <hip/hip_runtime.h>
#include <math.h>

// MySimpleRNN on MI355X — fp16 hi/lo split MFMA, BR=32 (weight-stream amortized).
// h = tanh(x_t@wx + b + h@wh), 64 steps, B=4096, NF=128, NH=512.
// Bottleneck analysis (prev round): per-block weight re-stream of 1.25 MB/step
// from L2 dominates (16.7 us/step vs 9.3 us L2 floor). Fix: 32 batch rows per
// block -> 128 blocks -> total L2 weight traffic halves; each weight fragment
// feeds 2 row-blocks of MFMAs. Weights repacked kb-major so one SGPR base +
// imm offsets covers the 8 loads of a kb iteration. Same 3-product hi/lo
// numerics as before; tanh via exp2+rcp (branch-free).
//
// mfma_f32_16x16x32_f16 layouts (verified learn_hip m89/m91/m120):
//   A: lane holds A[m=lane&15][k=(lane>>4)*8+j], j=0..7
//   B: lane holds B[k=(lane>>4)*8+j][n=lane&15]
//   C/D: reg r holds C[row=(lane>>4)*4+r][col=lane&15]

#define T_STEPS 64
#define NFD     128
#define NHD     512
#define BR      32
#define THREADS 512          // 8 waves, 2 per SIMD
#define LDH     (NHD + 8)    // padded fp16 row: 1040 B stride (16B-aligned)
#define LDX     (NFD + 8)    // 272 B stride

typedef _Float16 half8 __attribute__((ext_vector_type(8)));
typedef float float4v __attribute__((ext_vector_type(4)));

// ---- prep: split wh/wx into fp16 hi/lo, pack fragment-linear, kb-major ----
// whp: fi = ((w*16 + kb)*4 + nt)*64 + l ; element j of half8 fi <-
//      wh[(kb*32 + (l>>4)*8 + j)*512 + w*64 + nt*16 + (l&15)]
// wxp: fi = ((w*4  + kb)*4 + nt)*64 + l ; same with wx, kb 0..3
__global__ __launch_bounds__(256) void rnn_prep(
    const float* __restrict__ wh, const float* __restrict__ wx,
    _Float16* __restrict__ whp_hi, _Float16* __restrict__ whp_lo,
    _Float16* __restrict__ wxp_hi, _Float16* __restrict__ wxp_lo)
{
    int idx = blockIdx.x * 256 + threadIdx.x;   // 0..262143
    {
        int j  = idx & 7;
        int l  = (idx >> 3) & 63;
        int nt = (idx >> 9) & 3;
        int kb = (idx >> 11) & 15;
        int w  = idx >> 15;                     // 0..7
        int k  = kb * 32 + (l >> 4) * 8 + j;
        int n  = w * 64 + nt * 16 + (l & 15);
        float v = wh[k * NHD + n];
        _Float16 hi = (_Float16)v;
        whp_hi[idx] = hi;
        whp_lo[idx] = (_Float16)(v - (float)hi);
    }
    if (idx < 65536) {
        int j  = idx & 7;
        int l  = (idx >> 3) & 63;
        int nt = (idx >> 9) & 3;
        int kb = (idx >> 11) & 3;
        int w  = idx >> 13;                     // 0..7
        int k  = kb * 32 + (l >> 4) * 8 + j;
        int n  = w * 64 + nt * 16 + (l & 15);
        float v = wx[k * NHD + n];
        _Float16 hi = (_Float16)v;
        wxp_hi[idx] = hi;
        wxp_lo[idx] = (_Float16)(v - (float)hi);
    }
}

// branch-free tanh: clamp to +-9 (tanh(9)==1.0f in fp32), (e-1)/(e+1), e=2^(2x*log2e)
__device__ __forceinline__ float fast_tanh(float v) {
    float xc = fminf(fmaxf(v, -9.0f), 9.0f);
    float e  = __builtin_amdgcn_exp2f(xc * 2.8853900817779268f); // 2*log2(e)
    return (e - 1.0f) * __builtin_amdgcn_rcpf(e + 1.0f);
}

// ---- main fused recurrence ----
__global__ __launch_bounds__(THREADS, 2) void rnn_mfma(
    const float* __restrict__ x,
    const float* __restrict__ bias,
    const _Float16* __restrict__ whp_hi, const _Float16* __restrict__ whp_lo,
    const _Float16* __restrict__ wxp_hi, const _Float16* __restrict__ wxp_lo,
    float* __restrict__ out)
{
    __shared__ _Float16 sh_hhi[BR * LDH];   // 33280 B
    __shared__ _Float16 sh_hlo[BR * LDH];   // 33280 B
    __shared__ _Float16 sh_xhi[BR * LDX];   //  8704 B
    __shared__ _Float16 sh_xlo[BR * LDX];   //  8704 B  -> total 83968 B

    const int tid  = (int)threadIdx.x;
    const int lane = tid & 63;
    const int w    = tid >> 6;        // wave 0..7, owns cols [w*64, w*64+64)
    const int m    = lane & 15;       // A-row / C-col lane index
    const int quad = lane >> 4;
    const int row0 = (int)blockIdx.x * BR;

    // zero h
    for (int i = tid; i < BR * LDH; i += THREADS) {
        sh_hhi[i] = (_Float16)0.f;
        sh_hlo[i] = (_Float16)0.f;
    }

    // bias for this lane's 4 col-tiles (same for both row-blocks)
    float bv[4];
    #pragma unroll
    for (int nt = 0; nt < 4; ++nt) bv[nt] = bias[w * 64 + nt * 16 + m];

    // x prefetch: 512 threads cover 32 rows x 128 floats, 8 floats each
    const int xrow = tid >> 4;          // 0..31
    const int xcol = (tid & 15) * 8;    // 0..120
    const float* xptr = x + (size_t)(row0 + xrow) * (T_STEPS * NFD) + xcol;
    float4v px0 = *(const float4v*)xptr;
    float4v px1 = *(const float4v*)(xptr + 4);

    // wave-uniform weight bases (half8 units): fragments at base + (kb*4+nt)*64 + lane
    const half8* wxh = (const half8*)wxp_hi + (size_t)w * 1024;
    const half8* wxl = (const half8*)wxp_lo + (size_t)w * 1024;
    const half8* whh = (const half8*)whp_hi + (size_t)w * 4096;
    const half8* whl = (const half8*)whp_lo + (size_t)w * 4096;

    for (int t = 0; t < T_STEPS; ++t) {
        // stage x(t): split fp32 -> hi/lo fp16, one 16B write per array
        {
            half8 vh, vl;
            float xs[8] = {px0[0], px0[1], px0[2], px0[3],
                           px1[0], px1[1], px1[2], px1[3]};
            #pragma unroll
            for (int j = 0; j < 8; ++j) {
                _Float16 hi = (_Float16)xs[j];
                vh[j] = hi;
                vl[j] = (_Float16)(xs[j] - (float)hi);
            }
            *(half8*)&sh_xhi[xrow * LDX + xcol] = vh;
            *(half8*)&sh_xlo[xrow * LDX + xcol] = vl;
        }
        __syncthreads();   // x staged + h(t-1) writes visible

        if (t + 1 < T_STEPS) {
            px0 = *(const float4v*)(xptr + (t + 1) * NFD);
            px1 = *(const float4v*)(xptr + (t + 1) * NFD + 4);
        }

        float4v acc[2][4];
        #pragma unroll
        for (int rb = 0; rb < 2; ++rb)
            #pragma unroll
            for (int nt = 0; nt < 4; ++nt) {
                acc[rb][nt][0] = bv[nt]; acc[rb][nt][1] = bv[nt];
                acc[rb][nt][2] = bv[nt]; acc[rb][nt][3] = bv[nt];
            }

        // input projection: K = 128 -> 4 k-blocks of 32
        #pragma unroll
        for (int kb = 0; kb < 4; ++kb) {
            half8 a0h = *(const half8*)&sh_xhi[m * LDX + kb * 32 + quad * 8];
            half8 a0l = *(const half8*)&sh_xlo[m * LDX + kb * 32 + quad * 8];
            half8 a1h = *(const half8*)&sh_xhi[(16 + m) * LDX + kb * 32 + quad * 8];
            half8 a1l = *(const half8*)&sh_xlo[(16 + m) * LDX + kb * 32 + quad * 8];
            half8 bh[4], bl[4];
            #pragma unroll
            for (int nt = 0; nt < 4; ++nt) {
                bh[nt] = wxh[(kb * 4 + nt) * 64 + lane];
                bl[nt] = wxl[(kb * 4 + nt) * 64 + lane];
            }
            #pragma unroll
            for (int nt = 0; nt < 4; ++nt) {
                acc[0][nt] = __builtin_amdgcn_mfma_f32_16x16x32_f16(a0h, bh[nt], acc[0][nt], 0, 0, 0);
                acc[0][nt] = __builtin_amdgcn_mfma_f32_16x16x32_f16(a0l, bh[nt], acc[0][nt], 0, 0, 0);
                acc[0][nt] = __builtin_amdgcn_mfma_f32_16x16x32_f16(a0h, bl[nt], acc[0][nt], 0, 0, 0);
                acc[1][nt] = __builtin_amdgcn_mfma_f32_16x16x32_f16(a1h, bh[nt], acc[1][nt], 0, 0, 0);
                acc[1][nt] = __builtin_amdgcn_mfma_f32_16x16x32_f16(a1l, bh[nt], acc[1][nt], 0, 0, 0);
                acc[1][nt] = __builtin_amdgcn_mfma_f32_16x16x32_f16(a1h, bl[nt], acc[1][nt], 0, 0, 0);
            }
        }

        // recurrence: K = 512 -> 16 k-blocks of 32
        #pragma unroll 4
        for (int kb = 0; kb < 16; ++kb) {
            half8 a0h = *(const half8*)&sh_hhi[m * LDH + kb * 32 + quad * 8];
            half8 a0l = *(const half8*)&sh_hlo[m * LDH + kb * 32 + quad * 8];
            half8 a1h = *(const half8*)&sh_hhi[(16 + m) * LDH + kb * 32 + quad * 8];
            half8 a1l = *(const half8*)&sh_hlo[(16 + m) * LDH + kb * 32 + quad * 8];
            half8 bh[4], bl[4];
            #pragma unroll
            for (int nt = 0; nt < 4; ++nt) {
                bh[nt] = whh[(kb * 4 + nt) * 64 + lane];
                bl[nt] = whl[(kb * 4 + nt) * 64 + lane];
            }
            #pragma unroll
            for (int nt = 0; nt < 4; ++nt) {
                acc[0][nt] = __builtin_amdgcn_mfma_f32_16x16x32_f16(a0h, bh[nt], acc[0][nt], 0, 0, 0);
                acc[0][nt] = __builtin_amdgcn_mfma_f32_16x16x32_f16(a0l, bh[nt], acc[0][nt], 0, 0, 0);
                acc[0][nt] = __builtin_amdgcn_mfma_f32_16x16x32_f16(a0h, bl[nt], acc[0][nt], 0, 0, 0);
                acc[1][nt] = __builtin_amdgcn_mfma_f32_16x16x32_f16(a1h, bh[nt], acc[1][nt], 0, 0, 0);
                acc[1][nt] = __builtin_amdgcn_mfma_f32_16x16x32_f16(a1l, bh[nt], acc[1][nt], 0, 0, 0);
                acc[1][nt] = __builtin_amdgcn_mfma_f32_16x16x32_f16(a1h, bl[nt], acc[1][nt], 0, 0, 0);
            }
        }

        __syncthreads();   // all h/x reads for step t done

        // epilogue: tanh, split, write back (C row=quad*4+r, col=w*64+nt*16+m)
        if (t == T_STEPS - 1) {
            #pragma unroll
            for (int rb = 0; rb < 2; ++rb)
                #pragma unroll
                for (int nt = 0; nt < 4; ++nt)
                    #pragma unroll
                    for (int r = 0; r < 4; ++r)
                        out[(size_t)(row0 + rb * 16 + quad * 4 + r) * NHD + w * 64 + nt * 16 + m] =
                            fast_tanh(acc[rb][nt][r]);
        } else {
            #pragma unroll
            for (int rb = 0; rb < 2; ++rb)
                #pragma unroll
                for (int nt = 0; nt < 4; ++nt)
                    #pragma unroll
                    for (int r = 0; r < 4; ++r) {
                        float v = fast_tanh(acc[rb][nt][r]);
                        _Float16 hi = (_Float16)v;
                        int off = (rb * 16 + quad * 4 + r) * LDH + w * 64 + nt * 16 + m;
                        sh_hhi[off] = hi;
                        sh_hlo[off] = (_Float16)(v - (float)hi);
                    }
        }
    }
}

extern "C" void kernel_launch(void* const* d_in, const int* in_sizes, int n_in,
                              void* d_out, int out_size, void* d_ws, size_t ws_size,
                              hipStream_t stream) {
    const float* x    = (const float*)d_in[0];  // [B, 64, 128]
    const float* wx   = (const float*)d_in[1];  // [128, 512]
    const float* wh   = (const float*)d_in[2];  // [512, 512]
    const float* bias = (const float*)d_in[3];  // [512]
    float* out = (float*)d_out;                 // [B, 512]

    // workspace (fp16): whp_hi 512KB | whp_lo 512KB | wxp_hi 128KB | wxp_lo 128KB
    char* ws = (char*)d_ws;
    _Float16* whp_hi = (_Float16*)(ws);
    _Float16* whp_lo = (_Float16*)(ws + 524288);
    _Float16* wxp_hi = (_Float16*)(ws + 1048576);
    _Float16* wxp_lo = (_Float16*)(ws + 1048576 + 131072);

    rnn_prep<<<1024, 256, 0, stream>>>(wh, wx, whp_hi, whp_lo, wxp_hi, wxp_lo);

    const int B = in_sizes[0] / (T_STEPS * NFD);   // 4096
    rnn_mfma<<<B / BR, THREADS, 0, stream>>>(x, bias, whp_hi, whp_lo, wxp_hi, wxp_lo, out);
}

// Round 2
// 843.499 us; speedup vs baseline: 1.5040x; 1.5040x over previous
//
#include <hip/hip_runtime.h>
#include <math.h>

// MySimpleRNN on MI355X — fp16 hi/lo split MFMA, BR=16, 16 waves/CU.
// h = tanh(x_t@wx + b + h@wh), 64 steps, B=4096, NF=128, NH=512.
//
// Round-1 lesson: bottleneck is the PER-CU weight stream (1.25 MB/step through
// the L1 fill port / per-XCD L2, ~8.6-9.3 us/step floor), invariant to block
// count. Round 0 (8 waves/CU) hit ~55% of that floor. This round: 256 blocks
// (1/CU, all CUs active) x 1024 threads = 16 waves/CU (4/SIMD), each wave owns
// a 32-col slice -> 2x the independent load streams to hide L2 latency.
// __launch_bounds__(1024,4) caps VGPR at 128 for 4 waves/SIMD.
//
// mfma_f32_16x16x32_f16 layouts (verified learn_hip m89/m91/m120):
//   A: lane holds A[m=lane&15][k=(lane>>4)*8+j], j=0..7
//   B: lane holds B[k=(lane>>4)*8+j][n=lane&15]
//   C/D: reg r holds C[row=(lane>>4)*4+r][col=lane&15]

#define T_STEPS 64
#define NFD     128
#define NHD     512
#define BR      16
#define THREADS 1024         // 16 waves, 4 per SIMD
#define LDH     (NHD + 8)    // padded fp16 row: 1040 B stride (16B-aligned)
#define LDX     (NFD + 8)    // 272 B stride

typedef _Float16 half8 __attribute__((ext_vector_type(8)));
typedef _Float16 half2v __attribute__((ext_vector_type(2)));
typedef float float4v __attribute__((ext_vector_type(4)));

// ---- prep: split wh/wx into fp16 hi/lo, pack fragment-linear, kb-major ----
// (unchanged from round 1; layout is by 64-col wave-groups w8=0..7)
// whp: fi = ((w8*16 + kb)*4 + nt4)*64 + l ; element j of half8 fi <-
//      wh[(kb*32 + (l>>4)*8 + j)*512 + w8*64 + nt4*16 + (l&15)]
// wxp: fi = ((w8*4  + kb)*4 + nt4)*64 + l ; same with wx, kb 0..3
__global__ __launch_bounds__(256) void rnn_prep(
    const float* __restrict__ wh, const float* __restrict__ wx,
    _Float16* __restrict__ whp_hi, _Float16* __restrict__ whp_lo,
    _Float16* __restrict__ wxp_hi, _Float16* __restrict__ wxp_lo)
{
    int idx = blockIdx.x * 256 + threadIdx.x;   // 0..262143
    {
        int j  = idx & 7;
        int l  = (idx >> 3) & 63;
        int nt = (idx >> 9) & 3;
        int kb = (idx >> 11) & 15;
        int w  = idx >> 15;                     // 0..7
        int k  = kb * 32 + (l >> 4) * 8 + j;
        int n  = w * 64 + nt * 16 + (l & 15);
        float v = wh[k * NHD + n];
        _Float16 hi = (_Float16)v;
        whp_hi[idx] = hi;
        whp_lo[idx] = (_Float16)(v - (float)hi);
    }
    if (idx < 65536) {
        int j  = idx & 7;
        int l  = (idx >> 3) & 63;
        int nt = (idx >> 9) & 3;
        int kb = (idx >> 11) & 3;
        int w  = idx >> 13;                     // 0..7
        int k  = kb * 32 + (l >> 4) * 8 + j;
        int n  = w * 64 + nt * 16 + (l & 15);
        float v = wx[k * NHD + n];
        _Float16 hi = (_Float16)v;
        wxp_hi[idx] = hi;
        wxp_lo[idx] = (_Float16)(v - (float)hi);
    }
}

// branch-free tanh: clamp to +-9 (tanh(9)==1.0f in fp32), (e-1)/(e+1), e=2^(2x*log2e)
__device__ __forceinline__ float fast_tanh(float v) {
    float xc = fminf(fmaxf(v, -9.0f), 9.0f);
    float e  = __builtin_amdgcn_exp2f(xc * 2.8853900817779268f); // 2*log2(e)
    return (e - 1.0f) * __builtin_amdgcn_rcpf(e + 1.0f);
}

// ---- main fused recurrence ----
__global__ __launch_bounds__(THREADS, 4) void rnn_mfma(
    const float* __restrict__ x,
    const float* __restrict__ bias,
    const _Float16* __restrict__ whp_hi, const _Float16* __restrict__ whp_lo,
    const _Float16* __restrict__ wxp_hi, const _Float16* __restrict__ wxp_lo,
    float* __restrict__ out)
{
    __shared__ _Float16 sh_hhi[BR * LDH];   // 16640 B
    __shared__ _Float16 sh_hlo[BR * LDH];   // 16640 B
    __shared__ _Float16 sh_xhi[BR * LDX];   //  4352 B
    __shared__ _Float16 sh_xlo[BR * LDX];   //  4352 B  -> total 41984 B

    const int tid  = (int)threadIdx.x;
    const int lane = tid & 63;
    const int w    = tid >> 6;        // wave 0..15, owns cols [w*32, w*32+32)
    const int m    = lane & 15;       // A-row / C-col lane index
    const int quad = lane >> 4;
    const int row0 = (int)blockIdx.x * BR;

    // zero h
    for (int i = tid; i < BR * LDH; i += THREADS) {
        sh_hhi[i] = (_Float16)0.f;
        sh_hlo[i] = (_Float16)0.f;
    }

    // bias for this lane's 2 col-tiles
    float bv[2];
    #pragma unroll
    for (int nt = 0; nt < 2; ++nt) bv[nt] = bias[w * 32 + nt * 16 + m];

    // x prefetch: 1024 threads cover 16 rows x 128 floats, 2 floats each
    const int xrow = tid >> 6;          // 0..15
    const int xcol = (tid & 63) * 2;    // 0..126
    const float* xptr = x + (size_t)(row0 + xrow) * (T_STEPS * NFD) + xcol;
    float2 px = *(const float2*)xptr;

    // wave-uniform weight bases (half8 units); 32-col slice within the 64-col
    // packing group: base = (w>>1)*groupstride + (w&1)*128; fragment at
    // base + kb*256 + nt*64 + lane, nt in {0,1}.
    const half8* wxh = (const half8*)wxp_hi + (size_t)(w >> 1) * 1024 + (w & 1) * 128;
    const half8* wxl = (const half8*)wxp_lo + (size_t)(w >> 1) * 1024 + (w & 1) * 128;
    const half8* whh = (const half8*)whp_hi + (size_t)(w >> 1) * 4096 + (w & 1) * 128;
    const half8* whl = (const half8*)whp_lo + (size_t)(w >> 1) * 4096 + (w & 1) * 128;

    for (int t = 0; t < T_STEPS; ++t) {
        // stage x(t): split fp32 -> hi/lo fp16, one 4B write per array
        {
            half2v vh, vl;
            float xs[2] = {px.x, px.y};
            #pragma unroll
            for (int j = 0; j < 2; ++j) {
                _Float16 hi = (_Float16)xs[j];
                vh[j] = hi;
                vl[j] = (_Float16)(xs[j] - (float)hi);
            }
            *(half2v*)&sh_xhi[xrow * LDX + xcol] = vh;
            *(half2v*)&sh_xlo[xrow * LDX + xcol] = vl;
        }
        __syncthreads();   // x staged + h(t-1) writes visible

        if (t + 1 < T_STEPS) px = *(const float2*)(xptr + (t + 1) * NFD);

        float4v acc[2];
        #pragma unroll
        for (int nt = 0; nt < 2; ++nt) {
            acc[nt][0] = bv[nt]; acc[nt][1] = bv[nt];
            acc[nt][2] = bv[nt]; acc[nt][3] = bv[nt];
        }

        // input projection: K = 128 -> 4 k-blocks of 32
        #pragma unroll
        for (int kb = 0; kb < 4; ++kb) {
            half8 ah = *(const half8*)&sh_xhi[m * LDX + kb * 32 + quad * 8];
            half8 al = *(const half8*)&sh_xlo[m * LDX + kb * 32 + quad * 8];
            half8 bh0 = wxh[kb * 256 + lane];
            half8 bh1 = wxh[kb * 256 + 64 + lane];
            half8 bl0 = wxl[kb * 256 + lane];
            half8 bl1 = wxl[kb * 256 + 64 + lane];
            acc[0] = __builtin_amdgcn_mfma_f32_16x16x32_f16(ah, bh0, acc[0], 0, 0, 0);
            acc[0] = __builtin_amdgcn_mfma_f32_16x16x32_f16(al, bh0, acc[0], 0, 0, 0);
            acc[0] = __builtin_amdgcn_mfma_f32_16x16x32_f16(ah, bl0, acc[0], 0, 0, 0);
            acc[1] = __builtin_amdgcn_mfma_f32_16x16x32_f16(ah, bh1, acc[1], 0, 0, 0);
            acc[1] = __builtin_amdgcn_mfma_f32_16x16x32_f16(al, bh1, acc[1], 0, 0, 0);
            acc[1] = __builtin_amdgcn_mfma_f32_16x16x32_f16(ah, bl1, acc[1], 0, 0, 0);
        }

        // recurrence: K = 512 -> 16 k-blocks of 32
        #pragma unroll 4
        for (int kb = 0; kb < 16; ++kb) {
            half8 ah = *(const half8*)&sh_hhi[m * LDH + kb * 32 + quad * 8];
            half8 al = *(const half8*)&sh_hlo[m * LDH + kb * 32 + quad * 8];
            half8 bh0 = whh[kb * 256 + lane];
            half8 bh1 = whh[kb * 256 + 64 + lane];
            half8 bl0 = whl[kb * 256 + lane];
            half8 bl1 = whl[kb * 256 + 64 + lane];
            acc[0] = __builtin_amdgcn_mfma_f32_16x16x32_f16(ah, bh0, acc[0], 0, 0, 0);
            acc[0] = __builtin_amdgcn_mfma_f32_16x16x32_f16(al, bh0, acc[0], 0, 0, 0);
            acc[0] = __builtin_amdgcn_mfma_f32_16x16x32_f16(ah, bl0, acc[0], 0, 0, 0);
            acc[1] = __builtin_amdgcn_mfma_f32_16x16x32_f16(ah, bh1, acc[1], 0, 0, 0);
            acc[1] = __builtin_amdgcn_mfma_f32_16x16x32_f16(al, bh1, acc[1], 0, 0, 0);
            acc[1] = __builtin_amdgcn_mfma_f32_16x16x32_f16(ah, bl1, acc[1], 0, 0, 0);
        }

        __syncthreads();   // all h/x reads for step t done

        // epilogue: tanh, split, write back (C row=quad*4+r, col=w*32+nt*16+m)
        if (t == T_STEPS - 1) {
            #pragma unroll
            for (int nt = 0; nt < 2; ++nt)
                #pragma unroll
                for (int r = 0; r < 4; ++r)
                    out[(size_t)(row0 + quad * 4 + r) * NHD + w * 32 + nt * 16 + m] =
                        fast_tanh(acc[nt][r]);
        } else {
            #pragma unroll
            for (int nt = 0; nt < 2; ++nt) {
                #pragma unroll
                for (int r = 0; r < 4; ++r) {
                    float v = fast_tanh(acc[nt][r]);
                    _Float16 hi = (_Float16)v;
                    int off = (quad * 4 + r) * LDH + w * 32 + nt * 16 + m;
                    sh_hhi[off] = hi;
                    sh_hlo[off] = (_Float16)(v - (float)hi);
                }
            }
        }
    }
}

extern "C" void kernel_launch(void* const* d_in, const int* in_sizes, int n_in,
                              void* d_out, int out_size, void* d_ws, size_t ws_size,
                              hipStream_t stream) {
    const float* x    = (const float*)d_in[0];  // [B, 64, 128]
    const float* wx   = (const float*)d_in[1];  // [128, 512]
    const float* wh   = (const float*)d_in[2];  // [512, 512]
    const float* bias = (const float*)d_in[3];  // [512]
    float* out = (float*)d_out;                 // [B, 512]

    // workspace (fp16): whp_hi 512KB | whp_lo 512KB | wxp_hi 128KB | wxp_lo 128KB
    char* ws = (char*)d_ws;
    _Float16* whp_hi = (_Float16*)(ws);
    _Float16* whp_lo = (_Float16*)(ws + 524288);
    _Float16* wxp_hi = (_Float16*)(ws + 1048576);
    _Float16* wxp_lo = (_Float16*)(ws + 1048576 + 131072);

    rnn_prep<<<1024, 256, 0, stream>>>(wh, wx, whp_hi, whp_lo, wxp_hi, wxp_lo);

    const int B = in_sizes[0] / (T_STEPS * NFD);   // 4096
    rnn_mfma<<<B / BR, THREADS, 0, stream>>>(x, bias, whp_hi, whp_lo, wxp_hi, wxp_lo, out);
}